// Round 1
// baseline (1140.310 us; speedup 1.0000x reference)
//
#include <hip/hip_runtime.h>
#include <math.h>

// Problem constants
#define CNUM   64
#define HH     192
#define WW     192
#define NBATCH 8
#define HWSZ   (HH * WW)            // 36864
#define CHWSZ  (CNUM * HWSZ)        // 2359296
#define TOTALSZ ((size_t)NBATCH * CHWSZ)  // 18874368
#define QMAXF  127.0f
#define BNEPS  1e-5f

// Conv tiling
#define TWT 64      // tile width (pixels)
#define THT 16      // tile height
#define ICB 4       // input channels per LDS stage
#define OCB 16      // output channels per block
#define SROW 67     // padded LDS row: TWT+2 = 66 used, +1 pad breaks stride-66 bank conflict

// Workspace layout (float offsets)
#define OFF_QW1   0
#define OFF_QW2   36864
#define OFF_SUM1  73728
#define OFF_SSQ1  73792
#define OFF_SUM2  73856
#define OFF_SSQ2  73920
#define OFF_AB1   73984   // a[64], b[64]
#define OFF_AB2   74112
#define OFF_T1    74240
#define OFF_T2    (74240 + TOTALSZ)

// ---------------------------------------------------------------------------
// Kernel 1: weight fake-quant (blocks 0,1) + zero stats accumulators (block 2)
// ---------------------------------------------------------------------------
__global__ void wquant_kernel(const float* __restrict__ w1,
                              const float* __restrict__ w2,
                              float* __restrict__ qw1,
                              float* __restrict__ qw2,
                              float* __restrict__ stats /* 256 floats */) {
    const int tid = threadIdx.x;
    if (blockIdx.x == 2) {
        if (tid < 256) stats[tid] = 0.0f;
        return;
    }
    const float* w  = (blockIdx.x == 0) ? w1 : w2;
    float*       qw = (blockIdx.x == 0) ? qw1 : qw2;
    const int nel = CNUM * CNUM * 9;  // 36864

    float m = 0.0f;
    for (int i = tid; i < nel; i += 256) m = fmaxf(m, fabsf(w[i]));
    __shared__ float red[256];
    red[tid] = m;
    __syncthreads();
    for (int s = 128; s > 0; s >>= 1) {
        if (tid < s) red[tid] = fmaxf(red[tid], red[tid + s]);
        __syncthreads();
    }
    const float scale = red[0] / QMAXF;
    for (int i = tid; i < nel; i += 256) {
        float q = rintf(w[i] / scale);        // round half-to-even, matches jnp.round
        q = fminf(fmaxf(q, -QMAXF), QMAXF);
        qw[i] = q * scale;
    }
}

// ---------------------------------------------------------------------------
// Kernel 2/5: 3x3 conv, pad=1. Pre-op on loaded input: optional BN affine
// (ab != nullptr) then quant_act(alpha). Post-op: prelu (slope_p) or identity.
// Block: 256 threads -> 64x16 spatial tile x 16 output channels.
// Thread: 4 horizontal pixels x 16 oc (64 accumulators).
// ---------------------------------------------------------------------------
__global__ __launch_bounds__(256)
void conv3x3_kernel(const float* __restrict__ in,
                    const float* __restrict__ qw,   // [oc][ic][3][3]
                    float* __restrict__ outp,
                    const float* __restrict__ ab,      // nullptr or a[64],b[64]
                    const float* __restrict__ alpha_p, // quant clamp
                    const float* __restrict__ slope_p) // nullptr -> identity
{
    __shared__ __align__(16) float s_in[ICB][THT + 2][SROW];
    __shared__ __align__(16) float s_w[ICB][9][OCB];

    const int tid = threadIdx.x;
    const int x0 = blockIdx.x * TWT;       // 0..2 * 64
    const int y0 = blockIdx.y * THT;       // 0..11 * 16
    const int n   = blockIdx.z >> 2;       // 0..7
    const int ocg = blockIdx.z & 3;        // 0..3

    const float alpha = alpha_p[0];
    const float scale = alpha / QMAXF;
    const float slope = slope_p ? slope_p[0] : 1.0f;

    float acc[OCB][4];
#pragma unroll
    for (int o = 0; o < OCB; ++o)
#pragma unroll
        for (int p = 0; p < 4; ++p) acc[o][p] = 0.0f;

    const int ty = tid >> 4;          // 0..15
    const int xs = (tid & 15) * 4;    // 0,4,...,60

    for (int ic0 = 0; ic0 < CNUM; ic0 += ICB) {
        // ---- stage input tile (with halo, zero-pad, pre-op applied in-bounds)
        for (int idx = tid; idx < ICB * (THT + 2) * (TWT + 2); idx += 256) {
            const int icl = idx / ((THT + 2) * (TWT + 2));
            const int r   = idx % ((THT + 2) * (TWT + 2));
            const int iy  = r / (TWT + 2);
            const int ix  = r % (TWT + 2);
            const int gy = y0 + iy - 1;
            const int gx = x0 + ix - 1;
            float v = 0.0f;
            if (gy >= 0 && gy < HH && gx >= 0 && gx < WW) {
                const int ic = ic0 + icl;
                float raw = in[(size_t)n * CHWSZ + (size_t)ic * HWSZ + gy * WW + gx];
                if (ab) raw = ab[ic] * raw + ab[64 + ic];     // BN1 affine
                float xc = fminf(fmaxf(raw, -alpha), alpha);  // clamp
                v = rintf(xc / scale) * scale;                // fake-quant
            }
            s_in[icl][iy][ix] = v;
        }
        // ---- stage weights: s_w[icl][k][ocl]
        for (int idx = tid; idx < ICB * 9 * OCB; idx += 256) {
            const int icl = idx / (9 * OCB);
            const int r   = idx % (9 * OCB);
            const int k   = r / OCB;
            const int ocl = r % OCB;
            s_w[icl][k][ocl] = qw[(size_t)(ocg * OCB + ocl) * (CNUM * 9) + (ic0 + icl) * 9 + k];
        }
        __syncthreads();

        for (int icl = 0; icl < ICB; ++icl) {
            float win[3][6];
#pragma unroll
            for (int ky = 0; ky < 3; ++ky)
#pragma unroll
                for (int j = 0; j < 6; ++j)
                    win[ky][j] = s_in[icl][ty + ky][xs + j];
#pragma unroll
            for (int ky = 0; ky < 3; ++ky) {
#pragma unroll
                for (int kx = 0; kx < 3; ++kx) {
#pragma unroll
                    for (int o4 = 0; o4 < OCB / 4; ++o4) {
                        const float4 w4 = *(const float4*)&s_w[icl][ky * 3 + kx][o4 * 4];
#pragma unroll
                        for (int p = 0; p < 4; ++p) {
                            const float iv = win[ky][p + kx];
                            acc[o4 * 4 + 0][p] += iv * w4.x;
                            acc[o4 * 4 + 1][p] += iv * w4.y;
                            acc[o4 * 4 + 2][p] += iv * w4.z;
                            acc[o4 * 4 + 3][p] += iv * w4.w;
                        }
                    }
                }
            }
        }
        __syncthreads();
    }

    // ---- epilogue: prelu (or identity) + coalesced float4 store
#pragma unroll
    for (int ocl = 0; ocl < OCB; ++ocl) {
        const int oc = ocg * OCB + ocl;
        float4 v;
        float a0 = acc[ocl][0], a1 = acc[ocl][1], a2 = acc[ocl][2], a3 = acc[ocl][3];
        v.x = (a0 >= 0.0f) ? a0 : slope * a0;
        v.y = (a1 >= 0.0f) ? a1 : slope * a1;
        v.z = (a2 >= 0.0f) ? a2 : slope * a2;
        v.w = (a3 >= 0.0f) ? a3 : slope * a3;
        *(float4*)&outp[(size_t)n * CHWSZ + (size_t)oc * HWSZ + (y0 + ty) * WW + x0 + xs] = v;
    }
}

// ---------------------------------------------------------------------------
// Kernel 3/6: per-channel sum / sumsq over (N,H,W). grid = (64, 32)
// ---------------------------------------------------------------------------
__global__ void stats_kernel(const float* __restrict__ t,
                             float* __restrict__ sum,
                             float* __restrict__ sumsq) {
    const int tid = threadIdx.x;
    const int c = blockIdx.x;
    const int slice = blockIdx.y;     // 0..31
    const int n = slice >> 2;
    const int q = slice & 3;
    const int QSZ = HWSZ / 4;         // 9216
    const float* p = t + (size_t)n * CHWSZ + (size_t)c * HWSZ + (size_t)q * QSZ;

    float s = 0.0f, ss = 0.0f;
    for (int i = tid; i < QSZ; i += 256) {
        float v = p[i];
        s += v;
        ss += v * v;
    }
    __shared__ float rs[256], rss[256];
    rs[tid] = s; rss[tid] = ss;
    __syncthreads();
    for (int st = 128; st > 0; st >>= 1) {
        if (tid < st) { rs[tid] += rs[tid + st]; rss[tid] += rss[tid + st]; }
        __syncthreads();
    }
    if (tid == 0) {
        atomicAdd(sum + c, rs[0]);
        atomicAdd(sumsq + c, rss[0]);
    }
}

// ---------------------------------------------------------------------------
// Kernel 4/7: fold BN stats into per-channel affine a,b
// ---------------------------------------------------------------------------
__global__ void bnab_kernel(const float* __restrict__ sum,
                            const float* __restrict__ sumsq,
                            const float* __restrict__ gamma,
                            const float* __restrict__ beta,
                            float* __restrict__ ab) {
    const int c = threadIdx.x;  // 64 threads
    const float cnt = (float)(NBATCH * HWSZ);  // 294912
    const float mean = sum[c] / cnt;
    const float var  = sumsq[c] / cnt - mean * mean;
    const float inv  = 1.0f / sqrtf(var + BNEPS);
    const float a = gamma[c] * inv;
    ab[c] = a;
    ab[64 + c] = beta[c] - mean * a;
}

// ---------------------------------------------------------------------------
// Kernel 8: out = identity*shortcut + bn2(t2); also write 3 scalar tail outputs
// ---------------------------------------------------------------------------
__global__ void final_kernel(const float* __restrict__ identity,
                             const float* __restrict__ t2,
                             const float* __restrict__ ab2,
                             const float* __restrict__ shortcut_p,
                             const float* __restrict__ bits,
                             const float* __restrict__ f,
                             const float* __restrict__ bits_out,
                             float* __restrict__ out) {
    const size_t i4 = (size_t)blockIdx.x * 256 + threadIdx.x;  // < TOTALSZ/4
    const float sc = shortcut_p[0];
    const int c = (int)((i4 / (HWSZ / 4)) % CNUM);
    const float a = ab2[c];
    const float b = ab2[64 + c];
    const float4 idv = ((const float4*)identity)[i4];
    const float4 tv  = ((const float4*)t2)[i4];
    float4 o;
    o.x = idv.x * sc + a * tv.x + b;
    o.y = idv.y * sc + a * tv.y + b;
    o.z = idv.z * sc + a * tv.z + b;
    o.w = idv.w * sc + a * tv.w + b;
    ((float4*)out)[i4] = o;
    if (blockIdx.x == 0 && threadIdx.x == 0) {
        out[TOTALSZ + 0] = bits[0];
        out[TOTALSZ + 1] = f[0];
        out[TOTALSZ + 2] = bits_out[0];
    }
}

// ---------------------------------------------------------------------------
extern "C" void kernel_launch(void* const* d_in, const int* in_sizes, int n_in,
                              void* d_out, int out_size, void* d_ws, size_t ws_size,
                              hipStream_t stream) {
    const float* identity = (const float*)d_in[0];
    const float* bits     = (const float*)d_in[1];
    const float* f        = (const float*)d_in[2];
    const float* bits_out = (const float*)d_in[3];
    const float* w1       = (const float*)d_in[4];
    const float* w2       = (const float*)d_in[5];
    const float* alpha1   = (const float*)d_in[6];
    const float* alpha2   = (const float*)d_in[7];
    const float* gamma1   = (const float*)d_in[8];
    const float* beta1    = (const float*)d_in[9];
    const float* gamma2   = (const float*)d_in[10];
    const float* beta2    = (const float*)d_in[11];
    const float* prelu_a  = (const float*)d_in[12];
    const float* shortcut = (const float*)d_in[13];
    float* out = (float*)d_out;
    float* ws  = (float*)d_ws;

    float* qw1   = ws + OFF_QW1;
    float* qw2   = ws + OFF_QW2;
    float* sum1  = ws + OFF_SUM1;
    float* ssq1  = ws + OFF_SSQ1;
    float* sum2  = ws + OFF_SUM2;
    float* ssq2  = ws + OFF_SSQ2;
    float* ab1   = ws + OFF_AB1;
    float* ab2   = ws + OFF_AB2;
    float* t1    = ws + OFF_T1;
    float* t2    = ws + OFF_T2;
    float* stats = ws + OFF_SUM1;  // 256 floats zeroed by wquant block 2

    // 1. quantize weights + zero stats
    hipLaunchKernelGGL(wquant_kernel, dim3(3), dim3(256), 0, stream,
                       w1, w2, qw1, qw2, stats);
    // 2. conv1: qact(identity, a1) * qw1 -> prelu -> t1
    hipLaunchKernelGGL(conv3x3_kernel, dim3(WW / TWT, HH / THT, NBATCH * 4), dim3(256), 0, stream,
                       identity, qw1, t1, nullptr, alpha1, prelu_a);
    // 3. BN1 stats over t1
    hipLaunchKernelGGL(stats_kernel, dim3(CNUM, 32), dim3(256), 0, stream, t1, sum1, ssq1);
    // 4. BN1 affine coefficients
    hipLaunchKernelGGL(bnab_kernel, dim3(1), dim3(CNUM), 0, stream, sum1, ssq1, gamma1, beta1, ab1);
    // 5. conv2: qact(bn1(t1), a2) * qw2 -> t2
    hipLaunchKernelGGL(conv3x3_kernel, dim3(WW / TWT, HH / THT, NBATCH * 4), dim3(256), 0, stream,
                       t1, qw2, t2, ab1, alpha2, nullptr);
    // 6. BN2 stats over t2
    hipLaunchKernelGGL(stats_kernel, dim3(CNUM, 32), dim3(256), 0, stream, t2, sum2, ssq2);
    // 7. BN2 affine coefficients
    hipLaunchKernelGGL(bnab_kernel, dim3(1), dim3(CNUM), 0, stream, sum2, ssq2, gamma2, beta2, ab2);
    // 8. residual add + scalar tail
    hipLaunchKernelGGL(final_kernel, dim3((unsigned)(TOTALSZ / 4 / 256)), dim3(256), 0, stream,
                       identity, t2, ab2, shortcut, bits, f, bits_out, out);
}

// Round 2
// 572.300 us; speedup vs baseline: 1.9925x; 1.9925x over previous
//
#include <hip/hip_runtime.h>
#include <math.h>

// Problem constants
#define CNUM   64
#define HH     192
#define WW     192
#define NBATCH 8
#define HWSZ   (HH * WW)                  // 36864
#define CHWSZ  (CNUM * HWSZ)              // 2359296
#define TOTALSZ ((size_t)NBATCH * CHWSZ)  // 18874368
#define QMAXF  127.0f
#define BNEPS  1e-5f

typedef __attribute__((ext_vector_type(8))) short bf16x8;
typedef __attribute__((ext_vector_type(4))) float f32x4;

// Workspace layout (float offsets)
#define OFF_PK1   0          // packed bf16 weights conv1: 36864 shorts = 18432 floats
#define OFF_PK2   18432
#define OFF_SW    36864      // scale_w1, scale_w2
#define OFF_SUM1  36928
#define OFF_SSQ1  36992
#define OFF_SUM2  37056
#define OFF_SSQ2  37120
#define OFF_AB1   37184      // a[64], b[64]
#define OFF_AB2   37312
#define OFF_T1    37440
#define OFF_T2    (37440 + TOTALSZ)

// ---------------------------------------------------------------------------
// Kernel 1: weight fake-quant -> INTEGER bf16, pre-swizzled into MFMA B-frag
// lane order. pk[(((t*2+icb)*4+ocb)*64+l)*8+j] = q(w[oc][ic][t]) where
// oc=ocb*16+(l&15), ic=icb*32+((l>>4)&3)*8+j.  Block 2 zeroes stats.
// ---------------------------------------------------------------------------
__global__ void wquant_kernel(const float* __restrict__ w1,
                              const float* __restrict__ w2,
                              short* __restrict__ pk1,
                              short* __restrict__ pk2,
                              float* __restrict__ swout,
                              float* __restrict__ stats /* 256 floats */) {
    const int tid = threadIdx.x;
    if (blockIdx.x == 2) { stats[tid] = 0.0f; return; }
    const float* w  = blockIdx.x ? w2 : w1;
    short*       pk = blockIdx.x ? pk2 : pk1;

    float m = 0.0f;
    for (int i = tid; i < 36864; i += 256) m = fmaxf(m, fabsf(w[i]));
    __shared__ float red[256];
    red[tid] = m;
    __syncthreads();
    for (int s = 128; s > 0; s >>= 1) {
        if (tid < s) red[tid] = fmaxf(red[tid], red[tid + s]);
        __syncthreads();
    }
    const float scale = red[0] / QMAXF;
    if (tid == 0) swout[blockIdx.x] = scale;
    for (int i = tid; i < 36864; i += 256) {
        const int j   = i & 7;
        const int l   = (i >> 3) & 63;
        const int ocb = (i >> 9) & 3;
        const int icb = (i >> 11) & 1;
        const int t   = i >> 12;
        const int oc  = ocb * 16 + (l & 15);
        const int ic  = icb * 32 + ((l >> 4) & 3) * 8 + j;
        float q = rintf(w[oc * 576 + ic * 9 + t] / scale);
        q = fminf(fmaxf(q, -QMAXF), QMAXF);
        pk[i] = (short)(__builtin_bit_cast(unsigned, q) >> 16);  // exact: |q|<=127 integer
    }
}

// ---------------------------------------------------------------------------
// Kernel 2/5: 3x3 conv via bf16 MFMA implicit GEMM.
// Block: 256 thr (4 waves). Output tile: 4 rows x 64 px x 64 oc.
// Staging pre-op: optional BN affine (ab) -> clamp(+-alpha) -> q=rint(v/scale)
// stored as INTEGER bf16 (exact). MFMA accumulates exact integer dot in fp32;
// epilogue scales by (alpha/127)*(wmax/127), applies prelu (slope=1 if null).
// ---------------------------------------------------------------------------
__global__ __launch_bounds__(256)
void conv_mfma_kernel(const float* __restrict__ in,
                      const short* __restrict__ wpk,
                      const float* __restrict__ swp,     // 1 float: weight scale
                      float* __restrict__ outp,
                      const float* __restrict__ ab,      // nullptr or a[64],b[64]
                      const float* __restrict__ alpha_p,
                      const float* __restrict__ slope_p) // nullptr -> identity
{
    // [row 0..5][x 0..65][ic 0..63 + pad to 72]; x-stride 144B: b128 aligned,
    // lane-consecutive x => 4-bank stride => 2-way aliasing (free, m136)
    __shared__ short s_in[6 * 66 * 72];  // 57024 B

    const int tid = threadIdx.x;
    const int x0 = blockIdx.x * 64;
    const int y0 = blockIdx.y * 4;
    const int n  = blockIdx.z;

    const float alpha  = alpha_p[0];
    const float qscale = alpha / QMAXF;
    const float inv_qs = 1.0f / qscale;
    const bool  has_ab = (ab != nullptr);

    // ---- staging: 8 ic-groups x 6 rows x 66 x; one ds_write_b128 per elem-group
    for (int idx = tid; idx < 8 * 6 * 66; idx += 256) {
        const int icg = idx / 396;
        const int rem = idx % 396;
        const int r   = rem / 66;
        const int x   = rem % 66;
        const int gy = y0 + r - 1;
        const int gx = x0 + x - 1;
        const bool inb = (gy >= 0 && gy < HH && gx >= 0 && gx < WW);
        const float* src = in + (size_t)n * CHWSZ + (size_t)(icg * 8) * HWSZ + gy * WW + gx;
        bf16x8 pack;
#pragma unroll
        for (int j = 0; j < 8; ++j) {
            float v = 0.0f;
            if (inb) {
                v = src[(size_t)j * HWSZ];
                if (has_ab) { const int ic = icg * 8 + j; v = ab[ic] * v + ab[64 + ic]; }
                v = fminf(fmaxf(v, -alpha), alpha);
                v = rintf(v * inv_qs);           // integer in [-127,127]
            }
            pack[j] = (short)(__builtin_bit_cast(unsigned, v) >> 16);  // exact bf16
        }
        *(bf16x8*)&s_in[(r * 66 + x) * 72 + icg * 8] = pack;
    }
    __syncthreads();

    const int wave = tid >> 6;   // output row within tile
    const int lane = tid & 63;

    f32x4 acc[4][4];
#pragma unroll
    for (int m = 0; m < 4; ++m)
#pragma unroll
        for (int nb = 0; nb < 4; ++nb) acc[m][nb] = (f32x4){0.f, 0.f, 0.f, 0.f};

    const int icoff = (lane >> 4) * 8;
    const int xlane = lane & 15;

    for (int t = 0; t < 9; ++t) {
        const int ky = t / 3, kx = t % 3;
#pragma unroll
        for (int icb = 0; icb < 2; ++icb) {
            bf16x8 bfrag[4], afrag[4];
            const short* bp = wpk + (size_t)((t * 2 + icb) * 4) * 512 + lane * 8;
#pragma unroll
            for (int nb = 0; nb < 4; ++nb) bfrag[nb] = *(const bf16x8*)(bp + nb * 512);
            const int r  = wave + ky;
            const int ic = icb * 32 + icoff;
#pragma unroll
            for (int m = 0; m < 4; ++m) {
                const int x = m * 16 + xlane + kx;
                afrag[m] = *(const bf16x8*)&s_in[(r * 66 + x) * 72 + ic];
            }
#pragma unroll
            for (int m = 0; m < 4; ++m)
#pragma unroll
                for (int nb = 0; nb < 4; ++nb)
                    acc[m][nb] = __builtin_amdgcn_mfma_f32_16x16x32_bf16(
                        afrag[m], bfrag[nb], acc[m][nb], 0, 0, 0);
        }
    }

    // ---- epilogue: scale + prelu + float4 store
    // C layout (16x16): col = lane&15 (oc), row = (lane>>4)*4 + reg (x)
    const float sfin  = qscale * swp[0];
    const float slope = slope_p ? slope_p[0] : 1.0f;
    const int gy  = y0 + wave;
    const int gx0 = x0 + (lane >> 4) * 4;
#pragma unroll
    for (int m = 0; m < 4; ++m) {
#pragma unroll
        for (int nb = 0; nb < 4; ++nb) {
            const int oc = nb * 16 + (lane & 15);
            float4 v;
            float a0 = acc[m][nb][0] * sfin;
            float a1 = acc[m][nb][1] * sfin;
            float a2 = acc[m][nb][2] * sfin;
            float a3 = acc[m][nb][3] * sfin;
            v.x = (a0 >= 0.0f) ? a0 : slope * a0;
            v.y = (a1 >= 0.0f) ? a1 : slope * a1;
            v.z = (a2 >= 0.0f) ? a2 : slope * a2;
            v.w = (a3 >= 0.0f) ? a3 : slope * a3;
            *(float4*)&outp[(size_t)n * CHWSZ + (size_t)oc * HWSZ + gy * WW + gx0 + m * 16] = v;
        }
    }
}

// ---------------------------------------------------------------------------
// Kernel 3/6: per-channel sum / sumsq over (N,H,W). grid = (64, 32)
// ---------------------------------------------------------------------------
__global__ void stats_kernel(const float* __restrict__ t,
                             float* __restrict__ sum,
                             float* __restrict__ sumsq) {
    const int tid = threadIdx.x;
    const int c = blockIdx.x;
    const int slice = blockIdx.y;
    const int n = slice >> 2;
    const int q = slice & 3;
    const int QSZ = HWSZ / 4;
    const float* p = t + (size_t)n * CHWSZ + (size_t)c * HWSZ + (size_t)q * QSZ;

    float s = 0.0f, ss = 0.0f;
    for (int i = tid; i < QSZ; i += 256) {
        float v = p[i];
        s += v;
        ss += v * v;
    }
    __shared__ float rs[256], rss[256];
    rs[tid] = s; rss[tid] = ss;
    __syncthreads();
    for (int st = 128; st > 0; st >>= 1) {
        if (tid < st) { rs[tid] += rs[tid + st]; rss[tid] += rss[tid + st]; }
        __syncthreads();
    }
    if (tid == 0) {
        atomicAdd(sum + c, rs[0]);
        atomicAdd(sumsq + c, rss[0]);
    }
}

// ---------------------------------------------------------------------------
// Kernel 4/7: fold BN stats into per-channel affine a,b
// ---------------------------------------------------------------------------
__global__ void bnab_kernel(const float* __restrict__ sum,
                            const float* __restrict__ sumsq,
                            const float* __restrict__ gamma,
                            const float* __restrict__ beta,
                            float* __restrict__ ab) {
    const int c = threadIdx.x;
    const float cnt = (float)(NBATCH * HWSZ);
    const float mean = sum[c] / cnt;
    const float var  = sumsq[c] / cnt - mean * mean;
    const float inv  = 1.0f / sqrtf(var + BNEPS);
    const float a = gamma[c] * inv;
    ab[c] = a;
    ab[64 + c] = beta[c] - mean * a;
}

// ---------------------------------------------------------------------------
// Kernel 8: out = identity*shortcut + bn2(t2); plus 3 scalar tail outputs
// ---------------------------------------------------------------------------
__global__ void final_kernel(const float* __restrict__ identity,
                             const float* __restrict__ t2,
                             const float* __restrict__ ab2,
                             const float* __restrict__ shortcut_p,
                             const float* __restrict__ bits,
                             const float* __restrict__ f,
                             const float* __restrict__ bits_out,
                             float* __restrict__ out) {
    const size_t i4 = (size_t)blockIdx.x * 256 + threadIdx.x;
    const float sc = shortcut_p[0];
    const int c = (int)((i4 / (HWSZ / 4)) % CNUM);
    const float a = ab2[c];
    const float b = ab2[64 + c];
    const float4 idv = ((const float4*)identity)[i4];
    const float4 tv  = ((const float4*)t2)[i4];
    float4 o;
    o.x = idv.x * sc + a * tv.x + b;
    o.y = idv.y * sc + a * tv.y + b;
    o.z = idv.z * sc + a * tv.z + b;
    o.w = idv.w * sc + a * tv.w + b;
    ((float4*)out)[i4] = o;
    if (blockIdx.x == 0 && threadIdx.x == 0) {
        out[TOTALSZ + 0] = bits[0];
        out[TOTALSZ + 1] = f[0];
        out[TOTALSZ + 2] = bits_out[0];
    }
}

// ---------------------------------------------------------------------------
extern "C" void kernel_launch(void* const* d_in, const int* in_sizes, int n_in,
                              void* d_out, int out_size, void* d_ws, size_t ws_size,
                              hipStream_t stream) {
    const float* identity = (const float*)d_in[0];
    const float* bits     = (const float*)d_in[1];
    const float* f        = (const float*)d_in[2];
    const float* bits_out = (const float*)d_in[3];
    const float* w1       = (const float*)d_in[4];
    const float* w2       = (const float*)d_in[5];
    const float* alpha1   = (const float*)d_in[6];
    const float* alpha2   = (const float*)d_in[7];
    const float* gamma1   = (const float*)d_in[8];
    const float* beta1    = (const float*)d_in[9];
    const float* gamma2   = (const float*)d_in[10];
    const float* beta2    = (const float*)d_in[11];
    const float* prelu_a  = (const float*)d_in[12];
    const float* shortcut = (const float*)d_in[13];
    float* out = (float*)d_out;
    float* ws  = (float*)d_ws;

    short* pk1  = (short*)(ws + OFF_PK1);
    short* pk2  = (short*)(ws + OFF_PK2);
    float* sw   = ws + OFF_SW;
    float* sum1 = ws + OFF_SUM1;
    float* ssq1 = ws + OFF_SSQ1;
    float* sum2 = ws + OFF_SUM2;
    float* ssq2 = ws + OFF_SSQ2;
    float* ab1  = ws + OFF_AB1;
    float* ab2  = ws + OFF_AB2;
    float* t1   = ws + OFF_T1;
    float* t2   = ws + OFF_T2;
    float* stats = ws + OFF_SUM1;  // 256 floats zeroed by wquant block 2

    hipLaunchKernelGGL(wquant_kernel, dim3(3), dim3(256), 0, stream,
                       w1, w2, pk1, pk2, sw, stats);
    hipLaunchKernelGGL(conv_mfma_kernel, dim3(WW / 64, HH / 4, NBATCH), dim3(256), 0, stream,
                       identity, pk1, sw + 0, t1, nullptr, alpha1, prelu_a);
    hipLaunchKernelGGL(stats_kernel, dim3(CNUM, 32), dim3(256), 0, stream, t1, sum1, ssq1);
    hipLaunchKernelGGL(bnab_kernel, dim3(1), dim3(CNUM), 0, stream, sum1, ssq1, gamma1, beta1, ab1);
    hipLaunchKernelGGL(conv_mfma_kernel, dim3(WW / 64, HH / 4, NBATCH), dim3(256), 0, stream,
                       t1, pk2, sw + 1, t2, ab1, alpha2, nullptr);
    hipLaunchKernelGGL(stats_kernel, dim3(CNUM, 32), dim3(256), 0, stream, t2, sum2, ssq2);
    hipLaunchKernelGGL(bnab_kernel, dim3(1), dim3(CNUM), 0, stream, sum2, ssq2, gamma2, beta2, ab2);
    hipLaunchKernelGGL(final_kernel, dim3((unsigned)(TOTALSZ / 4 / 256)), dim3(256), 0, stream,
                       identity, t2, ab2, shortcut, bits, f, bits_out, out);
}

// Round 3
// 377.429 us; speedup vs baseline: 3.0213x; 1.5163x over previous
//
#include <hip/hip_runtime.h>
#include <hip/hip_bf16.h>
#include <math.h>

// Problem constants
#define CNUM   64
#define HH     192
#define WW     192
#define NBATCH 8
#define HWSZ   (HH * WW)                  // 36864
#define CHWSZ  (CNUM * HWSZ)              // 2359296
#define TOTALSZ ((size_t)NBATCH * CHWSZ)  // 18874368
#define QMAXF  127.0f
#define BNEPS  1e-5f
#define PW     194                        // padded spatial dim (1px zero border)

typedef __attribute__((ext_vector_type(8))) short bf16x8;
typedef __attribute__((ext_vector_type(4))) float f32x4;

// Workspace layout (float offsets)
#define OFF_PK1   0              // conv1 weights, B-frag swizzled bf16 (36864 shorts)
#define OFF_PK2   18432
#define OFF_SW    36864          // scale_w1, scale_w2
#define OFF_SUM1  36928
#define OFF_SSQ1  36992
#define OFF_SUM2  37056
#define OFF_SSQ2  37120
#define OFF_AB1   37184          // a[64], b[64]
#define OFF_AB2   37312
#define OFF_T1    37440                       // t1: bf16 NCHW, 18874368 shorts
#define OFF_Q1    (37440 + 9437184)           // q1: bf16 codes, padded NHWC swizzled
#define OFF_Q2    (OFF_Q1 + 9634816)          // q2: same
#define OFF_T2    OFF_Q1                      // t2 reuses q1 (dead after conv1)
// total = 28744256 floats = 115 MB

__device__ inline void gload16(const void* g, void* l) {
    __builtin_amdgcn_global_load_lds(
        (const __attribute__((address_space(1))) unsigned int*)g,
        (__attribute__((address_space(3))) unsigned int*)l, 16, 0, 0);
}
__device__ inline float bf2f(unsigned short u) {
    return __builtin_bit_cast(float, (unsigned)u << 16);
}

// ---------------------------------------------------------------------------
// Kernel 1: weight fake-quant -> INTEGER bf16, pre-swizzled into MFMA B-frag
// lane order (same as R2, verified). Block 2 zeroes the 4 stats vectors.
// ---------------------------------------------------------------------------
__global__ void wquant_kernel(const float* __restrict__ w1,
                              const float* __restrict__ w2,
                              short* __restrict__ pk1,
                              short* __restrict__ pk2,
                              float* __restrict__ swout,
                              float* __restrict__ stats /* 256 floats */) {
    const int tid = threadIdx.x;
    if (blockIdx.x == 2) { stats[tid] = 0.0f; return; }
    const float* w  = blockIdx.x ? w2 : w1;
    short*       pk = blockIdx.x ? pk2 : pk1;

    float m = 0.0f;
    for (int i = tid; i < 36864; i += 256) m = fmaxf(m, fabsf(w[i]));
    __shared__ float red[256];
    red[tid] = m;
    __syncthreads();
    for (int s = 128; s > 0; s >>= 1) {
        if (tid < s) red[tid] = fmaxf(red[tid], red[tid + s]);
        __syncthreads();
    }
    const float scale = red[0] / QMAXF;
    if (tid == 0) swout[blockIdx.x] = scale;
    for (int i = tid; i < 36864; i += 256) {
        const int j   = i & 7;
        const int l   = (i >> 3) & 63;
        const int ocb = (i >> 9) & 3;
        const int icb = (i >> 11) & 1;
        const int t   = i >> 12;
        const int oc  = ocb * 16 + (l & 15);
        const int ic  = icb * 32 + ((l >> 4) & 3) * 8 + j;
        float q = rintf(w[oc * 576 + ic * 9 + t] / scale);
        q = fminf(fmaxf(q, -QMAXF), QMAXF);
        pk[i] = (short)(__builtin_bit_cast(unsigned, q) >> 16);  // exact integer bf16
    }
}

// ---------------------------------------------------------------------------
// Kernel 2/5 (requant): fp32/bf16 NCHW  ->  bf16 integer codes, zero-padded
// swizzled NHWC  q[n][py][px][slot]  where slot = icg ^ (px & 7), groups of 8 ch.
// Pre-op: optional BN affine (ab) then clamp(+-alpha), rint(v*127/alpha).
// grid (3, 194, 8), block 256.
// ---------------------------------------------------------------------------
__global__ __launch_bounds__(256)
void requant_kernel(const void* __restrict__ inp, int in_is_bf16,
                    const float* __restrict__ ab,
                    const float* __restrict__ alpha_p,
                    short* __restrict__ q) {
    const int tid  = threadIdx.x;
    const int xblk = blockIdx.x;
    const int py   = blockIdx.y;
    const int n    = blockIdx.z;
    short* qrow = q + ((size_t)n * PW + py) * (PW * 64);

    if (py == 0 || py == PW - 1) {  // zero border rows (ws is re-poisoned every call)
        for (int i = xblk * 256 + tid; i < PW * 64 * 2 / 16; i += 768)
            ((int4*)qrow)[i] = make_int4(0, 0, 0, 0);
        return;
    }
    // zero border columns px=0 / px=193
    if (xblk == 0 && tid < 8) ((int4*)qrow)[tid] = make_int4(0, 0, 0, 0);
    if (xblk == 2 && tid < 8) ((int4*)(qrow + 193 * 64))[tid] = make_int4(0, 0, 0, 0);

    const int gy = py - 1;
    const float alpha  = alpha_p[0];
    const float inv_qs = QMAXF / alpha;

    __shared__ short s[64 * 72];  // [x][ic], stride 72 shorts (144B, b128-aligned)
    const int x   = tid & 63;
    const int icq = tid >> 6;
    const int gx  = xblk * 64 + x;
#pragma unroll
    for (int p = 0; p < 16; ++p) {
        const int ic = icq * 16 + p;
        const size_t off = ((size_t)n * CNUM + ic) * HWSZ + (size_t)gy * WW + gx;
        float v = in_is_bf16 ? bf2f(((const unsigned short*)inp)[off])
                             : ((const float*)inp)[off];
        if (ab) v = ab[ic] * v + ab[64 + ic];
        v = fminf(fmaxf(v, -alpha), alpha);
        v = rintf(v * inv_qs);                    // integer in [-127,127]
        s[x * 72 + ic] = (short)(__builtin_bit_cast(unsigned, v) >> 16);  // exact
    }
    __syncthreads();
    // write 512 16B chunks: (x, slot), slot-minor for coalescing
#pragma unroll
    for (int h = 0; h < 2; ++h) {
        const int t    = h * 256 + tid;
        const int xx   = t >> 3;
        const int slot = t & 7;
        const int px   = 1 + xblk * 64 + xx;
        const int g    = slot ^ (px & 7);
        const int4 val = *(const int4*)&s[xx * 72 + g * 8];
        *(int4*)(qrow + (size_t)px * 64 + slot * 8) = val;
    }
}

// ---------------------------------------------------------------------------
// Kernel 3/6: 3x3 conv via bf16 MFMA implicit GEMM, DMA-staged input.
// Block 256 thr: 4 rows x 64 px x 64 oc. Epilogue: scale, prelu(optional),
// bf16 NCHW store of t, fused per-channel sum/sumsq atomics (exact fp32).
// ---------------------------------------------------------------------------
__global__ __launch_bounds__(256, 3)
void conv_mfma_kernel(const short* __restrict__ q,     // padded swizzled NHWC codes
                      const short* __restrict__ wpk,
                      const float* __restrict__ swp,   // weight scale
                      const float* __restrict__ alpha_p,
                      const float* __restrict__ slope_p,  // nullptr -> identity
                      unsigned short* __restrict__ outp,  // bf16 NCHW
                      float* __restrict__ sum_g,
                      float* __restrict__ ssq_g) {
    __shared__ short s_in[6 * 66 * 64];   // 50688 B, [r][x][slot], slot = icg^(x&7)
    __shared__ float sred[4 * 64], ssred[4 * 64];

    const int tid = threadIdx.x;
    const int x0 = blockIdx.x * 64;
    const int y0 = blockIdx.y * 4;
    const int n  = blockIdx.z;

    // ---- DMA staging: rows py = y0..y0+5, px = x0..x0+65 (always in-bounds)
    const short* g0 = q + ((size_t)(n * PW + y0) * PW + x0) * 64;
    for (int c = tid; c < 3168; c += 256) {
        const int r = c / 528;
        const int w = c - r * 528;
        gload16(g0 + (size_t)r * (PW * 64) + w * 8, &s_in[c * 8]);
    }
    __syncthreads();

    const int wave  = tid >> 6;
    const int lane  = tid & 63;
    const int xlane = lane & 15;
    const int icgl  = lane >> 4;

    f32x4 acc[4][4];
#pragma unroll
    for (int m = 0; m < 4; ++m)
#pragma unroll
        for (int nb = 0; nb < 4; ++nb) acc[m][nb] = (f32x4){0.f, 0.f, 0.f, 0.f};

    for (int t = 0; t < 9; ++t) {
        const int ky = t / 3, kx = t % 3;
        const int r = wave + ky;
#pragma unroll
        for (int icb = 0; icb < 2; ++icb) {
            const int icg = icb * 4 + icgl;
            bf16x8 bfrag[4], afrag[4];
            const short* bp = wpk + (size_t)((t * 2 + icb) * 4) * 512 + lane * 8;
#pragma unroll
            for (int nb = 0; nb < 4; ++nb) bfrag[nb] = *(const bf16x8*)(bp + nb * 512);
#pragma unroll
            for (int m = 0; m < 4; ++m) {
                const int x = m * 16 + xlane + kx;
                afrag[m] = *(const bf16x8*)&s_in[(size_t)((r * 66 + x) * 8 + (icg ^ (x & 7))) * 8];
            }
#pragma unroll
            for (int m = 0; m < 4; ++m)
#pragma unroll
                for (int nb = 0; nb < 4; ++nb)
                    acc[m][nb] = __builtin_amdgcn_mfma_f32_16x16x32_bf16(
                        afrag[m], bfrag[nb], acc[m][nb], 0, 0, 0);
        }
    }

    // ---- epilogue: scale + prelu + bf16 store + fused stats
    const float sfin  = (alpha_p[0] / QMAXF) * swp[0];
    const float slope = slope_p ? slope_p[0] : 1.0f;
    const int gy  = y0 + wave;
    const int gx0 = x0 + icgl * 4;   // (lane>>4)*4
#pragma unroll
    for (int nb = 0; nb < 4; ++nb) {
        const int oc = nb * 16 + xlane;
        float s = 0.0f, ss = 0.0f;
#pragma unroll
        for (int m = 0; m < 4; ++m) {
            float v[4];
#pragma unroll
            for (int rgi = 0; rgi < 4; ++rgi) {
                float a = acc[m][nb][rgi] * sfin;
                a = (a >= 0.0f) ? a : slope * a;
                v[rgi] = a;
                s += a;
                ss += a * a;
            }
            ushort4 pk;
            pk.x = __builtin_bit_cast(unsigned short, __float2bfloat16(v[0]));
            pk.y = __builtin_bit_cast(unsigned short, __float2bfloat16(v[1]));
            pk.z = __builtin_bit_cast(unsigned short, __float2bfloat16(v[2]));
            pk.w = __builtin_bit_cast(unsigned short, __float2bfloat16(v[3]));
            *(ushort4*)&outp[(size_t)(n * CNUM + oc) * HWSZ + (size_t)gy * WW + gx0 + m * 16] = pk;
        }
        // reduce over the 4 lane-groups holding this channel
        s  += __shfl_xor(s, 16);  s  += __shfl_xor(s, 32);
        ss += __shfl_xor(ss, 16); ss += __shfl_xor(ss, 32);
        if (icgl == 0) { sred[wave * 64 + oc] = s; ssred[wave * 64 + oc] = ss; }
    }
    __syncthreads();
    if (tid < 64) {
        atomicAdd(sum_g + tid, sred[tid] + sred[64 + tid] + sred[128 + tid] + sred[192 + tid]);
    } else if (tid < 128) {
        const int c = tid - 64;
        atomicAdd(ssq_g + c, ssred[c] + ssred[64 + c] + ssred[128 + c] + ssred[192 + c]);
    }
}

// ---------------------------------------------------------------------------
// Kernel 4/7: fold BN stats into per-channel affine a,b
// ---------------------------------------------------------------------------
__global__ void bnab_kernel(const float* __restrict__ sum,
                            const float* __restrict__ sumsq,
                            const float* __restrict__ gamma,
                            const float* __restrict__ beta,
                            float* __restrict__ ab) {
    const int c = threadIdx.x;
    const float cnt = (float)(NBATCH * HWSZ);
    const float mean = sum[c] / cnt;
    const float var  = sumsq[c] / cnt - mean * mean;
    const float inv  = 1.0f / sqrtf(var + BNEPS);
    const float a = gamma[c] * inv;
    ab[c] = a;
    ab[64 + c] = beta[c] - mean * a;
}

// ---------------------------------------------------------------------------
// Kernel 8: out = identity*shortcut + bn2(t2[bf16]); plus 3 scalar tails
// ---------------------------------------------------------------------------
__global__ void final_kernel(const float* __restrict__ identity,
                             const unsigned short* __restrict__ t2,
                             const float* __restrict__ ab2,
                             const float* __restrict__ shortcut_p,
                             const float* __restrict__ bits,
                             const float* __restrict__ f,
                             const float* __restrict__ bits_out,
                             float* __restrict__ out) {
    const size_t i4 = (size_t)blockIdx.x * 256 + threadIdx.x;
    const float sc = shortcut_p[0];
    const int c = (int)((i4 / (HWSZ / 4)) % CNUM);
    const float a = ab2[c];
    const float b = ab2[64 + c];
    const float4 idv = ((const float4*)identity)[i4];
    const ushort4 tv = ((const ushort4*)t2)[i4];
    float4 o;
    o.x = idv.x * sc + a * bf2f(tv.x) + b;
    o.y = idv.y * sc + a * bf2f(tv.y) + b;
    o.z = idv.z * sc + a * bf2f(tv.z) + b;
    o.w = idv.w * sc + a * bf2f(tv.w) + b;
    ((float4*)out)[i4] = o;
    if (blockIdx.x == 0 && threadIdx.x == 0) {
        out[TOTALSZ + 0] = bits[0];
        out[TOTALSZ + 1] = f[0];
        out[TOTALSZ + 2] = bits_out[0];
    }
}

// ---------------------------------------------------------------------------
extern "C" void kernel_launch(void* const* d_in, const int* in_sizes, int n_in,
                              void* d_out, int out_size, void* d_ws, size_t ws_size,
                              hipStream_t stream) {
    const float* identity = (const float*)d_in[0];
    const float* bits     = (const float*)d_in[1];
    const float* f        = (const float*)d_in[2];
    const float* bits_out = (const float*)d_in[3];
    const float* w1       = (const float*)d_in[4];
    const float* w2       = (const float*)d_in[5];
    const float* alpha1   = (const float*)d_in[6];
    const float* alpha2   = (const float*)d_in[7];
    const float* gamma1   = (const float*)d_in[8];
    const float* beta1    = (const float*)d_in[9];
    const float* gamma2   = (const float*)d_in[10];
    const float* beta2    = (const float*)d_in[11];
    const float* prelu_a  = (const float*)d_in[12];
    const float* shortcut = (const float*)d_in[13];
    float* out = (float*)d_out;
    float* ws  = (float*)d_ws;

    short* pk1  = (short*)(ws + OFF_PK1);
    short* pk2  = (short*)(ws + OFF_PK2);
    float* sw   = ws + OFF_SW;
    float* sum1 = ws + OFF_SUM1;
    float* ssq1 = ws + OFF_SSQ1;
    float* sum2 = ws + OFF_SUM2;
    float* ssq2 = ws + OFF_SSQ2;
    float* ab1  = ws + OFF_AB1;
    float* ab2  = ws + OFF_AB2;
    unsigned short* t1 = (unsigned short*)(ws + OFF_T1);
    short*          q1 = (short*)(ws + OFF_Q1);
    short*          q2 = (short*)(ws + OFF_Q2);
    unsigned short* t2 = (unsigned short*)(ws + OFF_T2);  // reuses q1
    float* stats = ws + OFF_SUM1;

    // 1. weight quant + swizzle; zero stats accumulators
    hipLaunchKernelGGL(wquant_kernel, dim3(3), dim3(256), 0, stream,
                       w1, w2, pk1, pk2, sw, stats);
    // 2. identity -> q1 codes (padded swizzled NHWC)
    hipLaunchKernelGGL(requant_kernel, dim3(3, PW, NBATCH), dim3(256), 0, stream,
                       (const void*)identity, 0, (const float*)nullptr, alpha1, q1);
    // 3. conv1 + prelu -> t1 (bf16) + stats1
    hipLaunchKernelGGL(conv_mfma_kernel, dim3(3, HH / 4, NBATCH), dim3(256), 0, stream,
                       q1, pk1, sw + 0, alpha1, prelu_a, t1, sum1, ssq1);
    // 4. BN1 coefficients
    hipLaunchKernelGGL(bnab_kernel, dim3(1), dim3(CNUM), 0, stream, sum1, ssq1, gamma1, beta1, ab1);
    // 5. t1 -> q2 codes (BN1 affine + qact(alpha2))
    hipLaunchKernelGGL(requant_kernel, dim3(3, PW, NBATCH), dim3(256), 0, stream,
                       (const void*)t1, 1, ab1, alpha2, q2);
    // 6. conv2 -> t2 (bf16, overwrites q1) + stats2
    hipLaunchKernelGGL(conv_mfma_kernel, dim3(3, HH / 4, NBATCH), dim3(256), 0, stream,
                       q2, pk2, sw + 1, alpha2, (const float*)nullptr, t2, sum2, ssq2);
    // 7. BN2 coefficients
    hipLaunchKernelGGL(bnab_kernel, dim3(1), dim3(CNUM), 0, stream, sum2, ssq2, gamma2, beta2, ab2);
    // 8. residual + BN2 apply + scalar tail
    hipLaunchKernelGGL(final_kernel, dim3((unsigned)(TOTALSZ / 4 / 256)), dim3(256), 0, stream,
                       identity, t2, ab2, shortcut, bits, f, bits_out, out);
}

// Round 4
// 321.104 us; speedup vs baseline: 3.5512x; 1.1754x over previous
//
#include <hip/hip_runtime.h>
#include <hip/hip_bf16.h>
#include <math.h>

// Problem constants
#define CNUM   64
#define HH     192
#define WW     192
#define NBATCH 8
#define HWSZ   (HH * WW)                  // 36864
#define CHWSZ  (CNUM * HWSZ)              // 2359296
#define TOTALSZ ((size_t)NBATCH * CHWSZ)  // 18874368
#define QMAXF  127.0f
#define BNEPS  1e-5f
#define PW     194                        // padded spatial dim (1px zero border)

typedef __attribute__((ext_vector_type(8))) short bf16x8;
typedef __attribute__((ext_vector_type(4))) float f32x4;

// Workspace layout (float offsets)
#define OFF_PK1    0             // conv1 weights, B-frag swizzled bf16 (36864 shorts)
#define OFF_PK2    18432
#define OFF_STATS  36864         // sum1[256] ssq1[256] sum2[256] ssq2[256] wmax[2] = 1026 floats (memset 0)
#define OFF_SUM1   36864
#define OFF_SSQ1   37120
#define OFF_SUM2   37376
#define OFF_SSQ2   37632
#define OFF_WMAX   37888
#define OFF_SW     37890
#define OFF_AB1    37892         // a[64], b[64]
#define OFF_AB2    38020
#define OFF_T1     38148                      // t1: bf16 NCHW, 18874368 shorts
#define OFF_Q1     (38148 + 9437184)          // q1: bf16 codes, padded NHWC swizzled
#define OFF_Q2     (OFF_Q1 + 9634816)         // q2: same
#define OFF_T2     OFF_Q1                     // t2 reuses q1 (dead after conv1)

__device__ inline void gload16(const void* g, void* l) {
    __builtin_amdgcn_global_load_lds(
        (const __attribute__((address_space(1))) unsigned int*)g,
        (__attribute__((address_space(3))) unsigned int*)l, 16, 0, 0);
}
__device__ inline float bf2f(unsigned short u) {
    return __builtin_bit_cast(float, (unsigned)u << 16);
}

// ---------------------------------------------------------------------------
// Kernel 1a: weight absmax -> atomicMax on float bits (valid: values >= 0,
// accumulator memset to 0).  grid (18, 2), 8 elems/thread, float4 loads.
// ---------------------------------------------------------------------------
__global__ __launch_bounds__(256)
void wmax_kernel(const float* __restrict__ w1,
                 const float* __restrict__ w2,
                 unsigned* __restrict__ wmaxbits) {
    const int which = blockIdx.y;
    const float4* w4 = (const float4*)(which ? w2 : w1);
    const int b = (blockIdx.x * 256 + threadIdx.x) * 2;
    const float4 a = w4[b], c = w4[b + 1];
    float m = fmaxf(fmaxf(fmaxf(fabsf(a.x), fabsf(a.y)), fmaxf(fabsf(a.z), fabsf(a.w))),
                    fmaxf(fmaxf(fabsf(c.x), fabsf(c.y)), fmaxf(fabsf(c.z), fabsf(c.w))));
#pragma unroll
    for (int off = 1; off < 64; off <<= 1) m = fmaxf(m, __shfl_xor(m, off));
    if ((threadIdx.x & 63) == 0)
        atomicMax(wmaxbits + which, __builtin_bit_cast(unsigned, m));
}

// ---------------------------------------------------------------------------
// Kernel 1b: weight fake-quant -> INTEGER bf16, pre-swizzled into MFMA B-frag
// lane order: pk[(((t*2+icb)*4+ocb)*64+l)*8+j] = q(w[oc][ic][t]),
// oc=ocb*16+(l&15), ic=icb*32+((l>>4)&3)*8+j.  grid (18, 2).
// ---------------------------------------------------------------------------
__global__ __launch_bounds__(256)
void wpack_kernel(const float* __restrict__ w1,
                  const float* __restrict__ w2,
                  const unsigned* __restrict__ wmaxbits,
                  short* __restrict__ pk1,
                  short* __restrict__ pk2,
                  float* __restrict__ swout) {
    const int which = blockIdx.y;
    const float* w  = which ? w2 : w1;
    short*       pk = which ? pk2 : pk1;
    const float scale = __builtin_bit_cast(float, wmaxbits[which]) / QMAXF;
    if (blockIdx.x == 0 && threadIdx.x == 0) swout[which] = scale;
    const int i0 = (blockIdx.x * 256 + threadIdx.x) * 8;
#pragma unroll
    for (int k = 0; k < 8; ++k) {
        const int i = i0 + k;
        const int j   = i & 7;
        const int l   = (i >> 3) & 63;
        const int ocb = (i >> 9) & 3;
        const int icb = (i >> 11) & 1;
        const int t   = i >> 12;
        const int oc  = ocb * 16 + (l & 15);
        const int ic  = icb * 32 + ((l >> 4) & 3) * 8 + j;
        float q = rintf(w[oc * 576 + ic * 9 + t] / scale);
        q = fminf(fmaxf(q, -QMAXF), QMAXF);
        pk[i] = (short)(__builtin_bit_cast(unsigned, q) >> 16);  // exact integer bf16
    }
}

// ---------------------------------------------------------------------------
// Kernel 2/5 (requant): fp32/bf16 NCHW  ->  bf16 integer codes, zero-padded
// swizzled NHWC  q[n][py][px][slot], slot = icg ^ (px & 7), groups of 8 ch.
// grid (3, 194, 8), block 256.
// ---------------------------------------------------------------------------
__global__ __launch_bounds__(256)
void requant_kernel(const void* __restrict__ inp, int in_is_bf16,
                    const float* __restrict__ ab,
                    const float* __restrict__ alpha_p,
                    short* __restrict__ q) {
    const int tid  = threadIdx.x;
    const int xblk = blockIdx.x;
    const int py   = blockIdx.y;
    const int n    = blockIdx.z;
    short* qrow = q + ((size_t)n * PW + py) * (PW * 64);

    if (py == 0 || py == PW - 1) {  // zero border rows
        for (int i = xblk * 256 + tid; i < PW * 64 * 2 / 16; i += 768)
            ((int4*)qrow)[i] = make_int4(0, 0, 0, 0);
        return;
    }
    if (xblk == 0 && tid < 8) ((int4*)qrow)[tid] = make_int4(0, 0, 0, 0);
    if (xblk == 2 && tid < 8) ((int4*)(qrow + 193 * 64))[tid] = make_int4(0, 0, 0, 0);

    const int gy = py - 1;
    const float alpha  = alpha_p[0];
    const float inv_qs = QMAXF / alpha;

    __shared__ short s[64 * 72];  // [x][ic], stride 144B
    const int x   = tid & 63;
    const int icq = tid >> 6;
    const int gx  = xblk * 64 + x;
#pragma unroll
    for (int p = 0; p < 16; ++p) {
        const int ic = icq * 16 + p;
        const size_t off = ((size_t)n * CNUM + ic) * HWSZ + (size_t)gy * WW + gx;
        float v = in_is_bf16 ? bf2f(((const unsigned short*)inp)[off])
                             : ((const float*)inp)[off];
        if (ab) v = ab[ic] * v + ab[64 + ic];
        v = fminf(fmaxf(v, -alpha), alpha);
        v = rintf(v * inv_qs);                    // integer in [-127,127]
        s[x * 72 + ic] = (short)(__builtin_bit_cast(unsigned, v) >> 16);  // exact
    }
    __syncthreads();
#pragma unroll
    for (int h = 0; h < 2; ++h) {
        const int t    = h * 256 + tid;
        const int xx   = t >> 3;
        const int slot = t & 7;
        const int px   = 1 + xblk * 64 + xx;
        const int g    = slot ^ (px & 7);
        const int4 val = *(const int4*)&s[xx * 72 + g * 8];
        *(int4*)(qrow + (size_t)px * 64 + slot * 8) = val;
    }
}

// ---------------------------------------------------------------------------
// Kernel 3/6: 3x3 conv via bf16 MFMA implicit GEMM, DMA-staged input.
// Block 256 thr: 4 rows x 64 px x 64 oc. Epilogue: scale, prelu(optional),
// bf16 NCHW store, fused banked per-channel sum/sumsq atomics.
// ---------------------------------------------------------------------------
__global__ __launch_bounds__(256, 3)
void conv_mfma_kernel(const short* __restrict__ q,     // padded swizzled NHWC codes
                      const short* __restrict__ wpk,
                      const float* __restrict__ swp,   // weight scale
                      const float* __restrict__ alpha_p,
                      const float* __restrict__ slope_p,  // nullptr -> identity
                      unsigned short* __restrict__ outp,  // bf16 NCHW
                      float* __restrict__ sum_g,          // 4 banks x 64
                      float* __restrict__ ssq_g) {
    __shared__ short s_in[6 * 66 * 64];   // 50688 B, [r][x][slot], slot = icg^(x&7)
    __shared__ float sred[4 * 64], ssred[4 * 64];

    const int tid = threadIdx.x;
    const int x0 = blockIdx.x * 64;
    const int y0 = blockIdx.y * 4;
    const int n  = blockIdx.z;

    // ---- DMA staging: rows py = y0..y0+5, px = x0..x0+65 (always in-bounds)
    const short* g0 = q + ((size_t)(n * PW + y0) * PW + x0) * 64;
    for (int c = tid; c < 3168; c += 256) {
        const int r = c / 528;
        const int w = c - r * 528;
        gload16(g0 + (size_t)r * (PW * 64) + w * 8, &s_in[c * 8]);
    }
    __syncthreads();

    const int wave  = tid >> 6;
    const int lane  = tid & 63;
    const int xlane = lane & 15;
    const int icgl  = lane >> 4;

    f32x4 acc[4][4];
#pragma unroll
    for (int m = 0; m < 4; ++m)
#pragma unroll
        for (int nb = 0; nb < 4; ++nb) acc[m][nb] = (f32x4){0.f, 0.f, 0.f, 0.f};

#pragma unroll
    for (int t = 0; t < 9; ++t) {
        const int ky = t / 3, kx = t % 3;
        const int r = wave + ky;
#pragma unroll
        for (int icb = 0; icb < 2; ++icb) {
            const int icg = icb * 4 + icgl;
            bf16x8 bfrag[4], afrag[4];
            const short* bp = wpk + (size_t)((t * 2 + icb) * 4) * 512 + lane * 8;
#pragma unroll
            for (int nb = 0; nb < 4; ++nb) bfrag[nb] = *(const bf16x8*)(bp + nb * 512);
#pragma unroll
            for (int m = 0; m < 4; ++m) {
                const int x = m * 16 + xlane + kx;
                afrag[m] = *(const bf16x8*)&s_in[(size_t)((r * 66 + x) * 8 + (icg ^ (x & 7))) * 8];
            }
#pragma unroll
            for (int m = 0; m < 4; ++m)
#pragma unroll
                for (int nb = 0; nb < 4; ++nb)
                    acc[m][nb] = __builtin_amdgcn_mfma_f32_16x16x32_bf16(
                        afrag[m], bfrag[nb], acc[m][nb], 0, 0, 0);
        }
    }

    // ---- epilogue: scale + prelu + bf16 store + fused banked stats
    const float sfin  = (alpha_p[0] / QMAXF) * swp[0];
    const float slope = slope_p ? slope_p[0] : 1.0f;
    const int gy  = y0 + wave;
    const int gx0 = x0 + icgl * 4;
#pragma unroll
    for (int nb = 0; nb < 4; ++nb) {
        const int oc = nb * 16 + xlane;
        float s = 0.0f, ss = 0.0f;
#pragma unroll
        for (int m = 0; m < 4; ++m) {
            float v[4];
#pragma unroll
            for (int rgi = 0; rgi < 4; ++rgi) {
                float a = acc[m][nb][rgi] * sfin;
                a = (a >= 0.0f) ? a : slope * a;
                v[rgi] = a;
                s += a;
                ss += a * a;
            }
            ushort4 pk;
            pk.x = __builtin_bit_cast(unsigned short, __float2bfloat16(v[0]));
            pk.y = __builtin_bit_cast(unsigned short, __float2bfloat16(v[1]));
            pk.z = __builtin_bit_cast(unsigned short, __float2bfloat16(v[2]));
            pk.w = __builtin_bit_cast(unsigned short, __float2bfloat16(v[3]));
            *(ushort4*)&outp[(size_t)(n * CNUM + oc) * HWSZ + (size_t)gy * WW + gx0 + m * 16] = pk;
        }
        s  += __shfl_xor(s, 16);  s  += __shfl_xor(s, 32);
        ss += __shfl_xor(ss, 16); ss += __shfl_xor(ss, 32);
        if (icgl == 0) { sred[wave * 64 + oc] = s; ssred[wave * 64 + oc] = ss; }
    }
    __syncthreads();
    const int bank = (blockIdx.y ^ blockIdx.z) & 3;
    if (tid < 64) {
        atomicAdd(sum_g + bank * 64 + tid,
                  sred[tid] + sred[64 + tid] + sred[128 + tid] + sred[192 + tid]);
    } else if (tid < 128) {
        const int c = tid - 64;
        atomicAdd(ssq_g + bank * 64 + c,
                  ssred[c] + ssred[64 + c] + ssred[128 + c] + ssred[192 + c]);
    }
}

// ---------------------------------------------------------------------------
// Kernel 4/7: fold banked BN stats into per-channel affine a,b
// ---------------------------------------------------------------------------
__global__ void bnab_kernel(const float* __restrict__ sum,
                            const float* __restrict__ sumsq,
                            const float* __restrict__ gamma,
                            const float* __restrict__ beta,
                            float* __restrict__ ab) {
    const int c = threadIdx.x;
    const float cnt = (float)(NBATCH * HWSZ);
    const float sm = sum[c] + sum[64 + c] + sum[128 + c] + sum[192 + c];
    const float sq = sumsq[c] + sumsq[64 + c] + sumsq[128 + c] + sumsq[192 + c];
    const float mean = sm / cnt;
    const float var  = sq / cnt - mean * mean;
    const float inv  = 1.0f / sqrtf(var + BNEPS);
    const float a = gamma[c] * inv;
    ab[c] = a;
    ab[64 + c] = beta[c] - mean * a;
}

// ---------------------------------------------------------------------------
// Kernel 8: out = identity*shortcut + bn2(t2[bf16]); plus 3 scalar tails
// ---------------------------------------------------------------------------
__global__ void final_kernel(const float* __restrict__ identity,
                             const unsigned short* __restrict__ t2,
                             const float* __restrict__ ab2,
                             const float* __restrict__ shortcut_p,
                             const float* __restrict__ bits,
                             const float* __restrict__ f,
                             const float* __restrict__ bits_out,
                             float* __restrict__ out) {
    const size_t i4 = (size_t)blockIdx.x * 256 + threadIdx.x;
    const float sc = shortcut_p[0];
    const int c = (int)((i4 / (HWSZ / 4)) % CNUM);
    const float a = ab2[c];
    const float b = ab2[64 + c];
    const float4 idv = ((const float4*)identity)[i4];
    const ushort4 tv = ((const ushort4*)t2)[i4];
    float4 o;
    o.x = idv.x * sc + a * bf2f(tv.x) + b;
    o.y = idv.y * sc + a * bf2f(tv.y) + b;
    o.z = idv.z * sc + a * bf2f(tv.z) + b;
    o.w = idv.w * sc + a * bf2f(tv.w) + b;
    ((float4*)out)[i4] = o;
    if (blockIdx.x == 0 && threadIdx.x == 0) {
        out[TOTALSZ + 0] = bits[0];
        out[TOTALSZ + 1] = f[0];
        out[TOTALSZ + 2] = bits_out[0];
    }
}

// ---------------------------------------------------------------------------
extern "C" void kernel_launch(void* const* d_in, const int* in_sizes, int n_in,
                              void* d_out, int out_size, void* d_ws, size_t ws_size,
                              hipStream_t stream) {
    const float* identity = (const float*)d_in[0];
    const float* bits     = (const float*)d_in[1];
    const float* f        = (const float*)d_in[2];
    const float* bits_out = (const float*)d_in[3];
    const float* w1       = (const float*)d_in[4];
    const float* w2       = (const float*)d_in[5];
    const float* alpha1   = (const float*)d_in[6];
    const float* alpha2   = (const float*)d_in[7];
    const float* gamma1   = (const float*)d_in[8];
    const float* beta1    = (const float*)d_in[9];
    const float* gamma2   = (const float*)d_in[10];
    const float* beta2    = (const float*)d_in[11];
    const float* prelu_a  = (const float*)d_in[12];
    const float* shortcut = (const float*)d_in[13];
    float* out = (float*)d_out;
    float* ws  = (float*)d_ws;

    short*    pk1   = (short*)(ws + OFF_PK1);
    short*    pk2   = (short*)(ws + OFF_PK2);
    float*    sum1  = ws + OFF_SUM1;
    float*    ssq1  = ws + OFF_SSQ1;
    float*    sum2  = ws + OFF_SUM2;
    float*    ssq2  = ws + OFF_SSQ2;
    unsigned* wmaxb = (unsigned*)(ws + OFF_WMAX);
    float*    sw    = ws + OFF_SW;
    float*    ab1   = ws + OFF_AB1;
    float*    ab2   = ws + OFF_AB2;
    unsigned short* t1 = (unsigned short*)(ws + OFF_T1);
    short*          q1 = (short*)(ws + OFF_Q1);
    short*          q2 = (short*)(ws + OFF_Q2);
    unsigned short* t2 = (unsigned short*)(ws + OFF_T2);  // reuses q1

    // 0. zero stats banks + wmax accumulators (graph-capturable memset node)
    hipMemsetAsync(ws + OFF_STATS, 0, 1026 * sizeof(float), stream);
    // 1a. weight absmax (parallel)
    hipLaunchKernelGGL(wmax_kernel, dim3(18, 2), dim3(256), 0, stream, w1, w2, wmaxb);
    // 2. identity -> q1 codes (independent of wmax; hides its tail)
    hipLaunchKernelGGL(requant_kernel, dim3(3, PW, NBATCH), dim3(256), 0, stream,
                       (const void*)identity, 0, (const float*)nullptr, alpha1, q1);
    // 1b. weight pack (parallel)
    hipLaunchKernelGGL(wpack_kernel, dim3(18, 2), dim3(256), 0, stream,
                       w1, w2, wmaxb, pk1, pk2, sw);
    // 3. conv1 + prelu -> t1 (bf16) + stats1
    hipLaunchKernelGGL(conv_mfma_kernel, dim3(3, HH / 4, NBATCH), dim3(256), 0, stream,
                       q1, pk1, sw + 0, alpha1, prelu_a, t1, sum1, ssq1);
    // 4. BN1 coefficients
    hipLaunchKernelGGL(bnab_kernel, dim3(1), dim3(CNUM), 0, stream, sum1, ssq1, gamma1, beta1, ab1);
    // 5. t1 -> q2 codes (BN1 affine + qact(alpha2))
    hipLaunchKernelGGL(requant_kernel, dim3(3, PW, NBATCH), dim3(256), 0, stream,
                       (const void*)t1, 1, ab1, alpha2, q2);
    // 6. conv2 -> t2 (bf16, overwrites q1) + stats2
    hipLaunchKernelGGL(conv_mfma_kernel, dim3(3, HH / 4, NBATCH), dim3(256), 0, stream,
                       q2, pk2, sw + 1, alpha2, (const float*)nullptr, t2, sum2, ssq2);
    // 7. BN2 coefficients
    hipLaunchKernelGGL(bnab_kernel, dim3(1), dim3(CNUM), 0, stream, sum2, ssq2, gamma2, beta2, ab2);
    // 8. residual + BN2 apply + scalar tail
    hipLaunchKernelGGL(final_kernel, dim3((unsigned)(TOTALSZ / 4 / 256)), dim3(256), 0, stream,
                       identity, t2, ab2, shortcut, bits, f, bits_out, out);
}